// Round 2
// baseline (708.902 us; speedup 1.0000x reference)
//
#include <hip/hip_runtime.h>
#include <math.h>

// Problem: B=128, P=128, D=128, N=4096, fp32 in/out.
// probs = softmax(10*tanh((A@K)/sqrt(128)) + mask) over n.
constexpr int BB = 128;
constexpr int PP = 128;
constexpr int DD = 128;
constexpr int NN = 4096;
constexpr int NF4 = NN / 4;        // 1024 float4 per row
constexpr float kC = 10.0f;
constexpr float kInvSqrtD = 0.08838834764831845f;   // 1/sqrt(128)
constexpr float k2InvSqrtD = 0.1767766952966369f;   // 2/sqrt(128)

constexpr int NTHR = 1024;         // 16 waves; each thread owns ONE float4 column-block
constexpr int NWAVES = NTHR / 64;
constexpr int PT = 16;             // p-rows per block -> acc = 16 float4 = 64 VGPRs

__device__ __forceinline__ float4 f4_fma(float a, float4 k, float4 acc) {
    acc.x = fmaf(a, k.x, acc.x);
    acc.y = fmaf(a, k.y, acc.y);
    acc.z = fmaf(a, k.z, acc.z);
    acc.w = fmaf(a, k.w, acc.w);
    return acc;
}

// clipped = 10*tanh(s*kInvSqrtD) + m, via tanh(x) = 1 - 2/(e^{2x}+1)
__device__ __forceinline__ float clip1(float s, float m) {
    const float e2 = __expf(s * k2InvSqrtD);
    const float r = __builtin_amdgcn_rcpf(e2 + 1.0f);
    return fmaf(-2.0f * kC, r, kC) + m;
}

__device__ __forceinline__ float4 f4_clip_mask(float4 s, float4 m) {
    float4 r;
    r.x = clip1(s.x, m.x);
    r.y = clip1(s.y, m.y);
    r.z = clip1(s.z, m.z);
    r.w = clip1(s.w, m.w);
    return r;
}

__device__ __forceinline__ float f4_max(float4 s) {
    return fmaxf(fmaxf(s.x, s.y), fmaxf(s.z, s.w));
}

__device__ __forceinline__ float4 f4_expsub(float4 s, float mx) {
    float4 r;
    r.x = __expf(s.x - mx);
    r.y = __expf(s.y - mx);
    r.z = __expf(s.z - mx);
    r.w = __expf(s.w - mx);
    return r;
}

__device__ __forceinline__ float f4_sum(float4 s) {
    return (s.x + s.y) + (s.z + s.w);
}

__device__ __forceinline__ float4 f4_scale(float4 s, float v) {
    s.x *= v; s.y *= v; s.z *= v; s.w *= v;
    return s;
}

// One d-step: broadcast-read 16 A values (wave-uniform, conflict-free) and FMA
// into all 16 row accumulators with this thread's K float4.
__device__ __forceinline__ void fma_step(const float (&At)[DD][PT], int d,
                                         float4 k, float4 (&acc)[PT]) {
    const float4 a0 = *(const float4*)&At[d][0];
    const float4 a1 = *(const float4*)&At[d][4];
    const float4 a2 = *(const float4*)&At[d][8];
    const float4 a3 = *(const float4*)&At[d][12];
    const float av[PT] = {a0.x, a0.y, a0.z, a0.w,
                          a1.x, a1.y, a1.z, a1.w,
                          a2.x, a2.y, a2.z, a2.w,
                          a3.x, a3.y, a3.z, a3.w};
    #pragma unroll
    for (int p = 0; p < PT; ++p) acc[p] = f4_fma(av[p], k, acc[p]);
}

__global__ __launch_bounds__(NTHR, 4)   // 4 waves/EU -> VGPR cap 128, no spills by design
void fused_score_softmax(const float* __restrict__ A,   // [B][P][D]
                         const float* __restrict__ K,   // [B][D][N]
                         const float* __restrict__ M,   // [B][P][N]
                         float* __restrict__ O) {       // [B][P][N]
    __shared__ float At[DD][PT];            // A tile transposed: At[d][p] (8 KB)
    __shared__ float redmax[PT][NWAVES];    // [16][16] (1 KB)
    __shared__ float redsum[PT][NWAVES];

    // XCD-aware swizzle: consecutive blockIdx round-robin across XCDs, so the
    // 8 p-tiles of one batch land on one XCD -> K[b] (2 MB) stays in its 4 MB L2.
    const int l = blockIdx.x;
    const int xcd = l & 7;
    const int j = l >> 3;
    const int b = xcd + 8 * (j >> 3);       // bijective over [0,128)
    const int p_base = (j & 7) * PT;

    const int tid = (int)threadIdx.x;
    const int lane = tid & 63;
    const int wid = tid >> 6;

    // ---- Stage A tile (PT x DD) transposed into LDS (2 elements/thread) ----
    const float* Ab = A + ((size_t)b * PP + p_base) * DD;
    {
        int e = tid;
        At[e & (DD - 1)][e >> 7] = Ab[e];
        e += NTHR;
        At[e & (DD - 1)][e >> 7] = Ab[e];
    }
    __syncthreads();

    // ---- Matmul over d with 2-deep branchless K prefetch ----
    const float4* K4 = (const float4*)(K + (size_t)b * DD * NN);
    float4 acc[PT];
    #pragma unroll
    for (int p = 0; p < PT; ++p) acc[p] = make_float4(0.f, 0.f, 0.f, 0.f);

    float4 ka = K4[tid];
    float4 kb = K4[NF4 + tid];
    for (int d = 0; d < DD; d += 2) {
        const int dn = (d + 2) & (DD - 1);       // wraps to 0/1 on last iter (discarded)
        const float4 kc = K4[dn * NF4 + tid];
        const float4 kd = K4[(dn + 1) * NF4 + tid];
        fma_step(At, d, ka, acc);
        fma_step(At, d + 1, kb, acc);
        ka = kc;
        kb = kd;
    }

    // ---- Pointwise: clip (10*tanh) + mask; per-row thread-local max ----
    const size_t row_off = ((size_t)b * PP + p_base) * NN;
    const float4* M4 = (const float4*)(M + row_off);
    float4* O4 = (float4*)(O + row_off);

    float mx[PT];
    #pragma unroll
    for (int p = 0; p < PT; ++p) {
        const float4 m = M4[p * NF4 + tid];
        acc[p] = f4_clip_mask(acc[p], m);
        mx[p] = f4_max(acc[p]);
    }

    // wave max butterfly
    #pragma unroll
    for (int p = 0; p < PT; ++p) {
        float m = mx[p];
        #pragma unroll
        for (int off = 32; off > 0; off >>= 1)
            m = fmaxf(m, __shfl_xor(m, off));
        if (lane == 0) redmax[p][wid] = m;
    }
    __syncthreads();
    #pragma unroll
    for (int p = 0; p < PT; ++p) {
        const float4 r0 = *(const float4*)&redmax[p][0];
        const float4 r1 = *(const float4*)&redmax[p][4];
        const float4 r2 = *(const float4*)&redmax[p][8];
        const float4 r3 = *(const float4*)&redmax[p][12];
        mx[p] = fmaxf(fmaxf(f4_max(r0), f4_max(r1)), fmaxf(f4_max(r2), f4_max(r3)));
    }

    // ---- exp(s - max); per-row thread-local sum ----
    float sm[PT];
    #pragma unroll
    for (int p = 0; p < PT; ++p) {
        acc[p] = f4_expsub(acc[p], mx[p]);
        sm[p] = f4_sum(acc[p]);
    }
    #pragma unroll
    for (int p = 0; p < PT; ++p) {
        float s = sm[p];
        #pragma unroll
        for (int off = 32; off > 0; off >>= 1)
            s += __shfl_xor(s, off);
        if (lane == 0) redsum[p][wid] = s;
    }
    __syncthreads();

    // ---- normalize and write ----
    #pragma unroll
    for (int p = 0; p < PT; ++p) {
        const float4 r0 = *(const float4*)&redsum[p][0];
        const float4 r1 = *(const float4*)&redsum[p][4];
        const float4 r2 = *(const float4*)&redsum[p][8];
        const float4 r3 = *(const float4*)&redsum[p][12];
        const float s = (f4_sum(r0) + f4_sum(r1)) + (f4_sum(r2) + f4_sum(r3));
        const float inv = __builtin_amdgcn_rcpf(s);
        O4[p * NF4 + tid] = f4_scale(acc[p], inv);
    }
}

extern "C" void kernel_launch(void* const* d_in, const int* in_sizes, int n_in,
                              void* d_out, int out_size, void* d_ws, size_t ws_size,
                              hipStream_t stream) {
    const float* A = (const float*)d_in[0];   // mh_attn_out [128][128][128]
    const float* K = (const float*)d_in[1];   // single_head_key [128][128][4096]
    const float* M = (const float*)d_in[2];   // mask [128][128][4096]
    float* O = (float*)d_out;                 // probs [128][128][4096]

    const int nblocks = BB * (PP / PT);       // 128 * 8 = 1024
    fused_score_softmax<<<dim3(nblocks), dim3(NTHR), 0, stream>>>(A, K, M, O);
}

// Round 3
// 704.101 us; speedup vs baseline: 1.0068x; 1.0068x over previous
//
#include <hip/hip_runtime.h>
#include <math.h>

// Problem: B=128, P=128, D=128, N=4096, fp32 in/out.
// probs = softmax(10*tanh((A@K)/sqrt(128)) + mask) over n.
constexpr int BB = 128;
constexpr int PP = 128;
constexpr int DD = 128;
constexpr int NN = 4096;
constexpr int NF4 = NN / 4;        // 1024 float4 per row
constexpr float kC = 10.0f;
constexpr float k2InvSqrtD = 0.1767766952966369f;   // 2/sqrt(128)

constexpr int NTHR = 1024;         // 16 waves; each thread owns ONE float4 column-block
constexpr int NWAVES = NTHR / 64;
constexpr int PT = 16;             // p-rows per block -> acc = 16 float4 = 64 VGPRs

__device__ __forceinline__ float4 f4_fma(float a, float4 k, float4 acc) {
    acc.x = fmaf(a, k.x, acc.x);
    acc.y = fmaf(a, k.y, acc.y);
    acc.z = fmaf(a, k.z, acc.z);
    acc.w = fmaf(a, k.w, acc.w);
    return acc;
}

// clipped = 10*tanh(s/sqrt(128)) + m, via tanh(x) = 1 - 2/(e^{2x}+1)
__device__ __forceinline__ float clip1(float s, float m) {
    const float e2 = __expf(s * k2InvSqrtD);
    const float r = __builtin_amdgcn_rcpf(e2 + 1.0f);
    return fmaf(-2.0f * kC, r, kC) + m;
}

__device__ __forceinline__ float4 f4_clip_mask(float4 s, float4 m) {
    float4 r;
    r.x = clip1(s.x, m.x);
    r.y = clip1(s.y, m.y);
    r.z = clip1(s.z, m.z);
    r.w = clip1(s.w, m.w);
    return r;
}

__device__ __forceinline__ float f4_max(float4 s) {
    return fmaxf(fmaxf(s.x, s.y), fmaxf(s.z, s.w));
}

__device__ __forceinline__ float4 f4_expsub(float4 s, float mx) {
    float4 r;
    r.x = __expf(s.x - mx);
    r.y = __expf(s.y - mx);
    r.z = __expf(s.z - mx);
    r.w = __expf(s.w - mx);
    return r;
}

__device__ __forceinline__ float f4_sum(float4 s) {
    return (s.x + s.y) + (s.z + s.w);
}

__device__ __forceinline__ float4 f4_scale(float4 s, float v) {
    s.x *= v; s.y *= v; s.z *= v; s.w *= v;
    return s;
}

// One d-step: broadcast-read 16 A values (wave-uniform address -> LDS broadcast,
// conflict-free) and FMA into all 16 row accumulators with this thread's K float4.
__device__ __forceinline__ void fma_step(const float (&At)[DD][PT], int d,
                                         float4 k, float4 (&acc)[PT]) {
    const float4 a0 = *(const float4*)&At[d][0];
    const float4 a1 = *(const float4*)&At[d][4];
    const float4 a2 = *(const float4*)&At[d][8];
    const float4 a3 = *(const float4*)&At[d][12];
    acc[0]  = f4_fma(a0.x, k, acc[0]);
    acc[1]  = f4_fma(a0.y, k, acc[1]);
    acc[2]  = f4_fma(a0.z, k, acc[2]);
    acc[3]  = f4_fma(a0.w, k, acc[3]);
    acc[4]  = f4_fma(a1.x, k, acc[4]);
    acc[5]  = f4_fma(a1.y, k, acc[5]);
    acc[6]  = f4_fma(a1.z, k, acc[6]);
    acc[7]  = f4_fma(a1.w, k, acc[7]);
    acc[8]  = f4_fma(a2.x, k, acc[8]);
    acc[9]  = f4_fma(a2.y, k, acc[9]);
    acc[10] = f4_fma(a2.z, k, acc[10]);
    acc[11] = f4_fma(a2.w, k, acc[11]);
    acc[12] = f4_fma(a3.x, k, acc[12]);
    acc[13] = f4_fma(a3.y, k, acc[13]);
    acc[14] = f4_fma(a3.z, k, acc[14]);
    acc[15] = f4_fma(a3.w, k, acc[15]);
}

// NOTE on launch_bounds: empirically (R1/R2) hipcc treats the 2nd arg like
// CUDA's minBlocksPerCU: (512,2)->128 VGPR cap, (1024,4)->64 VGPR cap (spills!).
// (1024,1) gives a 128-VGPR cap under BOTH interpretations (1 block/CU = 4
// waves/EU; or min-1-wave clamped up to the structurally required 4).
__global__ __launch_bounds__(NTHR, 1)
void fused_score_softmax(const float* __restrict__ A,   // [B][P][D]
                         const float* __restrict__ K,   // [B][D][N]
                         const float* __restrict__ M,   // [B][P][N]
                         float* __restrict__ O) {       // [B][P][N]
    __shared__ float At[DD][PT];            // A tile transposed: At[d][p] (8 KB)
    __shared__ float redmax[PT][NWAVES];    // [16][16] (1 KB)
    __shared__ float redsum[PT][NWAVES];

    // XCD-aware swizzle: consecutive blockIdx round-robin across the 8 XCDs, so
    // the 8 p-tiles of one batch land on one XCD -> K[b] (2 MB) stays in its L2.
    const int l = blockIdx.x;
    const int xcd = l & 7;
    const int j = l >> 3;
    const int b = xcd + 8 * (j >> 3);       // bijective over [0,128)
    const int p_base = (j & 7) * PT;

    const int tid = (int)threadIdx.x;
    const int lane = tid & 63;
    const int wid = tid >> 6;

    // ---- Stage A tile (PT x DD) transposed into LDS (2 elements/thread) ----
    const float* Ab = A + ((size_t)b * PP + p_base) * DD;
    {
        int e = tid;
        At[e & (DD - 1)][e >> 7] = Ab[e];
        e += NTHR;
        At[e & (DD - 1)][e >> 7] = Ab[e];
    }
    __syncthreads();

    // ---- Matmul over d, 1-deep branchless K prefetch ----
    // Per d-step each wave issues 64 FMAs (128 issue-cycles); 4 waves/SIMD give
    // ~512 cycles issue-to-use distance for the prefetched load -> L2 latency hidden.
    const float4* K4 = (const float4*)(K + (size_t)b * DD * NN);
    float4 acc[PT];
    #pragma unroll
    for (int p = 0; p < PT; ++p) acc[p] = make_float4(0.f, 0.f, 0.f, 0.f);

    float4 kcur = K4[tid];
    for (int d = 0; d < DD; ++d) {
        const int dn = (d + 1) & (DD - 1);       // wraps to 0 on last iter (discarded)
        const float4 knext = K4[dn * NF4 + tid];
        fma_step(At, d, kcur, acc);
        kcur = knext;
    }

    // ---- Pointwise: clip (10*tanh) + mask; per-row thread-local max ----
    const size_t row_off = ((size_t)b * PP + p_base) * NN;
    const float4* M4 = (const float4*)(M + row_off);
    float4* O4 = (float4*)(O + row_off);

    float mx[PT];
    #pragma unroll
    for (int p = 0; p < PT; ++p) {
        const float4 m = M4[p * NF4 + tid];
        acc[p] = f4_clip_mask(acc[p], m);
        mx[p] = f4_max(acc[p]);
    }

    // wave max butterfly
    #pragma unroll
    for (int p = 0; p < PT; ++p) {
        float m = mx[p];
        #pragma unroll
        for (int off = 32; off > 0; off >>= 1)
            m = fmaxf(m, __shfl_xor(m, off));
        if (lane == 0) redmax[p][wid] = m;
    }
    __syncthreads();
    #pragma unroll
    for (int p = 0; p < PT; ++p) {
        const float4 r0 = *(const float4*)&redmax[p][0];
        const float4 r1 = *(const float4*)&redmax[p][4];
        const float4 r2 = *(const float4*)&redmax[p][8];
        const float4 r3 = *(const float4*)&redmax[p][12];
        mx[p] = fmaxf(fmaxf(f4_max(r0), f4_max(r1)), fmaxf(f4_max(r2), f4_max(r3)));
    }

    // ---- exp(s - max); per-row thread-local sum ----
    float sm[PT];
    #pragma unroll
    for (int p = 0; p < PT; ++p) {
        acc[p] = f4_expsub(acc[p], mx[p]);
        sm[p] = f4_sum(acc[p]);
    }
    #pragma unroll
    for (int p = 0; p < PT; ++p) {
        float s = sm[p];
        #pragma unroll
        for (int off = 32; off > 0; off >>= 1)
            s += __shfl_xor(s, off);
        if (lane == 0) redsum[p][wid] = s;
    }
    __syncthreads();

    // ---- normalize and write ----
    #pragma unroll
    for (int p = 0; p < PT; ++p) {
        const float4 r0 = *(const float4*)&redsum[p][0];
        const float4 r1 = *(const float4*)&redsum[p][4];
        const float4 r2 = *(const float4*)&redsum[p][8];
        const float4 r3 = *(const float4*)&redsum[p][12];
        const float s = (f4_sum(r0) + f4_sum(r1)) + (f4_sum(r2) + f4_sum(r3));
        const float inv = __builtin_amdgcn_rcpf(s);
        O4[p * NF4 + tid] = f4_scale(acc[p], inv);
    }
}

extern "C" void kernel_launch(void* const* d_in, const int* in_sizes, int n_in,
                              void* d_out, int out_size, void* d_ws, size_t ws_size,
                              hipStream_t stream) {
    const float* A = (const float*)d_in[0];   // mh_attn_out [128][128][128]
    const float* K = (const float*)d_in[1];   // single_head_key [128][128][4096]
    const float* M = (const float*)d_in[2];   // mask [128][128][4096]
    float* O = (float*)d_out;                 // probs [128][128][4096]

    const int nblocks = BB * (PP / PT);       // 128 * 8 = 1024
    fused_score_softmax<<<dim3(nblocks), dim3(NTHR), 0, stream>>>(A, K, M, O);
}

// Round 4
// 467.160 us; speedup vs baseline: 1.5175x; 1.5072x over previous
//
#include <hip/hip_runtime.h>
#include <math.h>

// Problem: B=128, P=128, D=128, N=4096, fp32 in/out.
// probs = softmax(10*tanh((A@K)/sqrt(128)) + mask) over n.
constexpr int BB = 128;
constexpr int PP = 128;
constexpr int DD = 128;
constexpr int NN = 4096;
constexpr int NF4 = NN / 4;        // 1024 float4 per row
constexpr float kC = 10.0f;
constexpr float k2InvSqrtD = 0.1767766952966369f;   // 2/sqrt(128)

// Empirical VGPR-cap law on this toolchain (R1-R3): 1024-thr blocks are capped
// at 64 VGPRs no matter the 2nd launch_bounds arg; 512-thr blocks with (512,2)
// got 128. So: 512 threads, and keep live registers ~100 by design.
constexpr int NTHR = 512;          // 8 waves
constexpr int NWAVES = NTHR / 64;
constexpr int PT = 8;              // p-rows per block -> acc = 8x2 float4 = 64 VGPRs

__device__ __forceinline__ float4 f4_fma(float a, float4 k, float4 acc) {
    acc.x = fmaf(a, k.x, acc.x);
    acc.y = fmaf(a, k.y, acc.y);
    acc.z = fmaf(a, k.z, acc.z);
    acc.w = fmaf(a, k.w, acc.w);
    return acc;
}

// clipped = 10*tanh(s/sqrt(128)) + m, via tanh(x) = 1 - 2/(e^{2x}+1)
__device__ __forceinline__ float clip1(float s, float m) {
    const float e2 = __expf(s * k2InvSqrtD);
    const float r = __builtin_amdgcn_rcpf(e2 + 1.0f);
    return fmaf(-2.0f * kC, r, kC) + m;
}

__device__ __forceinline__ float4 f4_clip_mask(float4 s, float4 m) {
    float4 r;
    r.x = clip1(s.x, m.x);
    r.y = clip1(s.y, m.y);
    r.z = clip1(s.z, m.z);
    r.w = clip1(s.w, m.w);
    return r;
}

__device__ __forceinline__ float f4_max(float4 s) {
    return fmaxf(fmaxf(s.x, s.y), fmaxf(s.z, s.w));
}

__device__ __forceinline__ float4 f4_expsub(float4 s, float mx) {
    float4 r;
    r.x = __expf(s.x - mx);
    r.y = __expf(s.y - mx);
    r.z = __expf(s.z - mx);
    r.w = __expf(s.w - mx);
    return r;
}

__device__ __forceinline__ float f4_sum(float4 s) {
    return (s.x + s.y) + (s.z + s.w);
}

__device__ __forceinline__ float4 f4_scale(float4 s, float v) {
    s.x *= v; s.y *= v; s.z *= v; s.w *= v;
    return s;
}

__global__ __launch_bounds__(NTHR, 2)   // empirically: 128-VGPR cap (R1)
void fused_score_softmax(const float* __restrict__ A,   // [B][P][D]
                         const float* __restrict__ K,   // [B][D][N]
                         const float* __restrict__ M,   // [B][P][N]
                         float* __restrict__ O) {       // [B][P][N]
    __shared__ float At[DD][PT];            // A tile transposed: At[d][p] (4 KB)
    __shared__ float redmax[PT][NWAVES];    // [8][8]
    __shared__ float redsum[PT][NWAVES];

    // XCD-aware swizzle: the 16 p-tiles of one batch land on one XCD (blocks with
    // equal l%8 dispatch to the same XCD in j order), so the batch's K rows are
    // shared through that XCD's L2 while its 16 blocks stream d in near-lockstep.
    const int l = blockIdx.x;
    const int xcd = l & 7;
    const int j = l >> 3;                   // 0..255 per XCD
    const int b = xcd + 8 * (j >> 4);       // bijective over [0,128)
    const int p_base = (j & 15) * PT;

    const int tid = (int)threadIdx.x;
    const int lane = tid & 63;
    const int wid = tid >> 6;

    // ---- Stage A tile (PT x DD) transposed into LDS (2 elements/thread) ----
    const float* Ab = A + ((size_t)b * PP + p_base) * DD;
    {
        int e = tid;
        At[e & (DD - 1)][e >> 7] = Ab[e];
        e += NTHR;
        At[e & (DD - 1)][e >> 7] = Ab[e];
    }
    __syncthreads();

    // ---- Matmul over d, 1-deep branchless K prefetch, 2 n-chunks/thread ----
    const float4* K4 = (const float4*)(K + (size_t)b * DD * NN);
    float4 acc0[PT], acc1[PT];
    #pragma unroll
    for (int p = 0; p < PT; ++p) {
        acc0[p] = make_float4(0.f, 0.f, 0.f, 0.f);
        acc1[p] = make_float4(0.f, 0.f, 0.f, 0.f);
    }

    float4 ka = K4[tid];
    float4 kb = K4[NTHR + tid];
    for (int d = 0; d < DD; ++d) {
        const int dn = (d + 1) & (DD - 1);       // wraps on last iter (discarded)
        const float4 kna = K4[dn * NF4 + tid];
        const float4 knb = K4[dn * NF4 + NTHR + tid];

        const float4 a0 = *(const float4*)&At[d][0];   // wave-uniform -> broadcast
        const float4 a1 = *(const float4*)&At[d][4];
        acc0[0] = f4_fma(a0.x, ka, acc0[0]);  acc1[0] = f4_fma(a0.x, kb, acc1[0]);
        acc0[1] = f4_fma(a0.y, ka, acc0[1]);  acc1[1] = f4_fma(a0.y, kb, acc1[1]);
        acc0[2] = f4_fma(a0.z, ka, acc0[2]);  acc1[2] = f4_fma(a0.z, kb, acc1[2]);
        acc0[3] = f4_fma(a0.w, ka, acc0[3]);  acc1[3] = f4_fma(a0.w, kb, acc1[3]);
        acc0[4] = f4_fma(a1.x, ka, acc0[4]);  acc1[4] = f4_fma(a1.x, kb, acc1[4]);
        acc0[5] = f4_fma(a1.y, ka, acc0[5]);  acc1[5] = f4_fma(a1.y, kb, acc1[5]);
        acc0[6] = f4_fma(a1.z, ka, acc0[6]);  acc1[6] = f4_fma(a1.z, kb, acc1[6]);
        acc0[7] = f4_fma(a1.w, ka, acc0[7]);  acc1[7] = f4_fma(a1.w, kb, acc1[7]);
        ka = kna;
        kb = knb;
    }

    // ---- Pointwise: clip (10*tanh) + mask; per-row thread-local max ----
    const size_t row_off = ((size_t)b * PP + p_base) * NN;
    const float4* M4 = (const float4*)(M + row_off);
    float4* O4 = (float4*)(O + row_off);

    float mx[PT];
    #pragma unroll
    for (int p = 0; p < PT; ++p) {
        const float4 m0 = M4[p * NF4 + tid];
        const float4 m1 = M4[p * NF4 + NTHR + tid];
        acc0[p] = f4_clip_mask(acc0[p], m0);
        acc1[p] = f4_clip_mask(acc1[p], m1);
        mx[p] = fmaxf(f4_max(acc0[p]), f4_max(acc1[p]));
    }

    // wave max butterfly
    #pragma unroll
    for (int p = 0; p < PT; ++p) {
        float m = mx[p];
        #pragma unroll
        for (int off = 32; off > 0; off >>= 1)
            m = fmaxf(m, __shfl_xor(m, off));
        if (lane == 0) redmax[p][wid] = m;
    }
    __syncthreads();
    #pragma unroll
    for (int p = 0; p < PT; ++p) {
        const float4 r0 = *(const float4*)&redmax[p][0];
        const float4 r1 = *(const float4*)&redmax[p][4];
        mx[p] = fmaxf(f4_max(r0), f4_max(r1));
    }

    // ---- exp(s - max); per-row thread-local sum ----
    float sm[PT];
    #pragma unroll
    for (int p = 0; p < PT; ++p) {
        acc0[p] = f4_expsub(acc0[p], mx[p]);
        acc1[p] = f4_expsub(acc1[p], mx[p]);
        sm[p] = f4_sum(acc0[p]) + f4_sum(acc1[p]);
    }
    #pragma unroll
    for (int p = 0; p < PT; ++p) {
        float s = sm[p];
        #pragma unroll
        for (int off = 32; off > 0; off >>= 1)
            s += __shfl_xor(s, off);
        if (lane == 0) redsum[p][wid] = s;
    }
    __syncthreads();

    // ---- normalize and write ----
    #pragma unroll
    for (int p = 0; p < PT; ++p) {
        const float4 r0 = *(const float4*)&redsum[p][0];
        const float4 r1 = *(const float4*)&redsum[p][4];
        const float s = f4_sum(r0) + f4_sum(r1);
        const float inv = __builtin_amdgcn_rcpf(s);
        O4[p * NF4 + tid] = f4_scale(acc0[p], inv);
        O4[p * NF4 + NTHR + tid] = f4_scale(acc1[p], inv);
    }
}

extern "C" void kernel_launch(void* const* d_in, const int* in_sizes, int n_in,
                              void* d_out, int out_size, void* d_ws, size_t ws_size,
                              hipStream_t stream) {
    const float* A = (const float*)d_in[0];   // mh_attn_out [128][128][128]
    const float* K = (const float*)d_in[1];   // single_head_key [128][128][4096]
    const float* M = (const float*)d_in[2];   // mask [128][128][4096]
    float* O = (float*)d_out;                 // probs [128][128][4096]

    const int nblocks = BB * (PP / PT);       // 128 * 16 = 2048
    fused_score_softmax<<<dim3(nblocks), dim3(NTHR), 0, stream>>>(A, K, M, O);
}